// Round 7
// baseline (1875.160 us; speedup 1.0000x reference)
//
#include <hip/hip_runtime.h>
#include <math.h>

typedef unsigned short u16;
typedef __attribute__((ext_vector_type(8))) short bf16x8;
typedef __attribute__((ext_vector_type(4))) float f32x4;

// ---------------- constants ----------------
#define BB 2
#define SS 2048
#define HH 2560
#define NH 8
#define NKV 4
#define HD 256
#define INTER 10240
#define SW 1024
#define MM 4096              // B*S tokens
#define QD 2048              // NH*HD
#define KD 1024              // NKV*HD
#define NEGF (-3.0e38f)

// ---------------- helpers ----------------
__device__ __forceinline__ u16 f2bf(float f) {
  unsigned int x = __float_as_uint(f);
  x = (x + 0x7fffu + ((x >> 16) & 1u)) >> 16;
  return (u16)x;
}
__device__ __forceinline__ float bf2f(u16 u) {
  return __uint_as_float(((unsigned int)u) << 16);
}
__device__ __forceinline__ f32x4 mfma_bf16(bf16x8 a, bf16x8 b, f32x4 c) {
  return __builtin_amdgcn_mfma_f32_16x16x32_bf16(a, b, c, 0, 0, 0);
}
__device__ __forceinline__ void gld_lds16(const u16* g, u16* l) {
  __builtin_amdgcn_global_load_lds(
      (const __attribute__((address_space(1))) unsigned int*)g,
      (__attribute__((address_space(3))) unsigned int*)l, 16, 0, 0);
}
__device__ __forceinline__ float gelu_tanh(float x) {
  float t = tanhf(0.7978845608028654f * (x + 0.044715f * x * x * x));
  return 0.5f * x * (1.0f + t);
}
__device__ __forceinline__ float block_sum(float v, float* red) {
  #pragma unroll
  for (int off = 32; off; off >>= 1) v += __shfl_xor(v, off);
  __syncthreads();
  if ((threadIdx.x & 63) == 0) red[threadIdx.x >> 6] = v;
  __syncthreads();
  return red[0] + red[1] + red[2] + red[3];
}

// ---------------- transpose fp32[R][C] -> bf16[C][R] ----------------
__global__ __launch_bounds__(256)
void k_transpose_w(const float* __restrict__ in, u16* __restrict__ out, int R, int C) {
  __shared__ float tile[32][33];
  int tx = threadIdx.x, ty = threadIdx.y;
  int c0 = blockIdx.x * 32, r0 = blockIdx.y * 32;
  #pragma unroll
  for (int j = ty; j < 32; j += 8)
    tile[j][tx] = in[(size_t)(r0 + j) * C + c0 + tx];
  __syncthreads();
  #pragma unroll
  for (int j = ty; j < 32; j += 8)
    out[(size_t)(c0 + j) * R + r0 + tx] = f2bf(tile[tx][j]);
}

// V part of qkv_bf16 [tok][4096] -> v_t bf16 [b][kv][HD][S]  (pure u16 transpose)
__global__ __launch_bounds__(256)
void k_transpose_v(const u16* __restrict__ qkv, u16* __restrict__ v_t) {
  __shared__ u16 tile[32][33];
  int tx = threadIdx.x, ty = threadIdx.y;
  int z = blockIdx.z;            // b*4 + kv
  int b = z >> 2, kv = z & 3;
  const u16* ip = qkv + (size_t)b * SS * 4096 + 3072 + kv * 256;
  u16* op = v_t + (size_t)z * HD * SS;
  int s0 = blockIdx.x * 32, d0 = blockIdx.y * 32;
  #pragma unroll
  for (int j = ty; j < 32; j += 8)
    tile[j][tx] = ip[(size_t)(s0 + j) * 4096 + d0 + tx];
  __syncthreads();
  #pragma unroll
  for (int j = ty; j < 32; j += 8)
    op[(size_t)(d0 + j) * SS + s0 + tx] = tile[tx][j];
}

// ---------------- RMSNorm(hidden, ln_in) -> bf16 ----------------
__global__ __launch_bounds__(256)
void k_rms_in(const float* __restrict__ x, const float* __restrict__ w,
              u16* __restrict__ out) {
  __shared__ float red[4];
  int row = blockIdx.x, tid = threadIdx.x;
  const float* xr = x + (size_t)row * HH;
  float v[10], ss = 0.f;
  #pragma unroll
  for (int i = 0; i < 10; ++i) { v[i] = xr[tid + i * 256]; ss += v[i] * v[i]; }
  ss = block_sum(ss, red);
  float inv = rsqrtf(ss * (1.0f / HH) + 1e-6f);
  #pragma unroll
  for (int i = 0; i < 10; ++i)
    out[(size_t)row * HH + tid + i * 256] = f2bf((1.0f + w[tid + i * 256]) * v[i] * inv);
}

// hidden = res + RMS(y, w1); xn = bf16(RMS(hidden, w2))
__global__ __launch_bounds__(256)
void k_resid2(const float* __restrict__ res, const float* __restrict__ y,
              const float* __restrict__ w1, const float* __restrict__ w2,
              float* __restrict__ hidden, u16* __restrict__ xn) {
  __shared__ float red[4];
  int row = blockIdx.x, tid = threadIdx.x;
  const float* yr = y + (size_t)row * HH;
  const float* rr = res + (size_t)row * HH;
  float yv[10], ss = 0.f;
  #pragma unroll
  for (int i = 0; i < 10; ++i) { yv[i] = yr[tid + i * 256]; ss += yv[i] * yv[i]; }
  ss = block_sum(ss, red);
  float inv1 = rsqrtf(ss * (1.0f / HH) + 1e-6f);
  float t[10], ss2 = 0.f;
  #pragma unroll
  for (int i = 0; i < 10; ++i) {
    int e = tid + i * 256;
    t[i] = rr[e] + (1.0f + w1[e]) * yv[i] * inv1;
    hidden[(size_t)row * HH + e] = t[i];
    ss2 += t[i] * t[i];
  }
  ss2 = block_sum(ss2, red);
  float inv2 = rsqrtf(ss2 * (1.0f / HH) + 1e-6f);
  #pragma unroll
  for (int i = 0; i < 10; ++i) {
    int e = tid + i * 256;
    xn[(size_t)row * HH + e] = f2bf((1.0f + w2[e]) * t[i] * inv2);
  }
}

// io += RMS(mlp, w)   (in-place on d_out which holds hidden)
__global__ __launch_bounds__(256)
void k_final(float* io, const float* __restrict__ mlp, const float* __restrict__ w) {
  __shared__ float red[4];
  int row = blockIdx.x, tid = threadIdx.x;
  const float* mr = mlp + (size_t)row * HH;
  float v[10], ss = 0.f;
  #pragma unroll
  for (int i = 0; i < 10; ++i) { v[i] = mr[tid + i * 256]; ss += v[i] * v[i]; }
  ss = block_sum(ss, red);
  float inv = rsqrtf(ss * (1.0f / HH) + 1e-6f);
  #pragma unroll
  for (int i = 0; i < 10; ++i) {
    int e = tid + i * 256;
    io[(size_t)row * HH + e] += (1.0f + w[e]) * v[i] * inv;
  }
}

// ---------------- per-head RMSNorm + RoPE (bf16 QKV input), q scaled ----------------
__global__ __launch_bounds__(256)
void k_qknorm_rope(const u16* __restrict__ qkv, const float* __restrict__ qn,
                   const float* __restrict__ kn, const int* __restrict__ pid,
                   u16* __restrict__ q_bf, u16* __restrict__ k_bf) {
  int gw = blockIdx.x * 4 + (threadIdx.x >> 6);
  int l = threadIdx.x & 63;
  int tok = gw / 12, hs = gw - tok * 12;       // 12 = 8 q heads + 4 k heads
  const u16* src; const float* wn; u16* dst; float sc;
  if (hs < 8) {
    src = qkv + (size_t)tok * 4096 + hs * 256;
    wn = qn; dst = q_bf + (size_t)tok * QD + hs * 256; sc = 0.0625f;  // 256^-0.5
  } else {
    int kh = hs - 8;
    src = qkv + (size_t)tok * 4096 + 2048 + kh * 256;
    wn = kn; dst = k_bf + (size_t)tok * KD + kh * 256; sc = 1.0f;
  }
  int i = l * 2;  // handles dims i, i+1, i+128, i+129
  unsigned int u1 = *(const unsigned int*)(src + i);
  unsigned int u2 = *(const unsigned int*)(src + 128 + i);
  float x1x = bf2f((u16)u1), x1y = bf2f((u16)(u1 >> 16));
  float x2x = bf2f((u16)u2), x2y = bf2f((u16)(u2 >> 16));
  float ss = x1x * x1x + x1y * x1y + x2x * x2x + x2y * x2y;
  #pragma unroll
  for (int off = 32; off; off >>= 1) ss += __shfl_xor(ss, off);
  float inv = rsqrtf(ss * (1.0f / HD) + 1e-6f);
  float n1x = (1.0f + wn[i]) * x1x * inv;
  float n1y = (1.0f + wn[i + 1]) * x1y * inv;
  float n2x = (1.0f + wn[i + 128]) * x2x * inv;
  float n2y = (1.0f + wn[i + 129]) * x2y * inv;
  float pos = (float)pid[tok];
  // theta^(-2d/HD) = exp2(-2d/HD * log2(theta)); log2(10000)=13.2877123795
  float f0 = exp2f((float)(2 * i)     * (-13.287712379549449f / HD));
  float f1 = exp2f((float)(2 * i + 2) * (-13.287712379549449f / HD));
  float a0 = pos * f0, a1 = pos * f1;
  float c0 = cosf(a0), s0 = sinf(a0), c1 = cosf(a1), s1 = sinf(a1);
  dst[i]       = f2bf((n1x * c0 - n2x * s0) * sc);
  dst[i + 1]   = f2bf((n1y * c1 - n2y * s1) * sc);
  dst[i + 128] = f2bf((n2x * c0 + n1x * s0) * sc);
  dst[i + 129] = f2bf((n2y * c1 + n1y * s1) * sc);
}

// ---------------- GEMM: C[M,N] = A[M,K] * Bt[N,K]^T  (bf16 in, fp32 acc) ----------------
// EPI 0: fp32 out; 1: bf16 out; 2: bf16 out = gelu(acc) * bf2f(aux)
// NOTE: Cv/aux intentionally NOT __restrict__ — EPI==2 uses them aliased (in-place).
// T1: XCD-aware chunked block swizzle (bijective when nwg%8==0; identity otherwise)
template <int EPI>
__global__ __launch_bounds__(256, 2)
void k_gemm(const u16* __restrict__ A, const u16* __restrict__ Bt,
            void* Cv, const u16* aux,
            int M, int N, int K) {
  __shared__ u16 As[128 * 64];
  __shared__ u16 Bs[128 * 64];
  const int tid = threadIdx.x;
  const int w = tid >> 6, l = tid & 63;
  const int lr = l & 15, lg = l >> 4;
  const int wr = w >> 1, wc = w & 1;

  int nwg = gridDim.x * gridDim.y;
  int bid = blockIdx.y * gridDim.x + blockIdx.x;
  if ((nwg & 7) == 0) bid = (bid & 7) * (nwg >> 3) + (bid >> 3);  // T1 XCD swizzle
  const int bm = bid / gridDim.x, bn = bid % gridDim.x;

  f32x4 acc[4][4];
  #pragma unroll
  for (int a = 0; a < 4; ++a)
    #pragma unroll
    for (int b = 0; b < 4; ++b) acc[a][b] = (f32x4){0.f, 0.f, 0.f, 0.f};

  const int sr = l >> 3;            // row within 8-row staging slot
  const int sk = (l & 7) * 8;       // k offset within 64
  const u16* Ag = A + (size_t)(bm * 128) * K;
  const u16* Bg = Bt + (size_t)(bn * 128) * K;

  for (int kt = 0; kt < K; kt += 64) {
    __syncthreads();
    #pragma unroll
    for (int j = 0; j < 4; ++j) {
      int slot = w * 4 + j;
      gld_lds16(Ag + (size_t)(slot * 8 + sr) * K + kt + sk, &As[slot * 512 + l * 8]);
      gld_lds16(Bg + (size_t)(slot * 8 + sr) * K + kt + sk, &Bs[slot * 512 + l * 8]);
    }
    __syncthreads();
    #pragma unroll
    for (int ks = 0; ks < 2; ++ks) {
      bf16x8 af[4], bfr[4];
      #pragma unroll
      for (int mb = 0; mb < 4; ++mb)
        af[mb] = *(const bf16x8*)&As[(wr * 64 + mb * 16 + lr) * 64 + ks * 32 + lg * 8];
      #pragma unroll
      for (int nb = 0; nb < 4; ++nb)
        bfr[nb] = *(const bf16x8*)&Bs[(wc * 64 + nb * 16 + lr) * 64 + ks * 32 + lg * 8];
      #pragma unroll
      for (int mb = 0; mb < 4; ++mb)
        #pragma unroll
        for (int nb = 0; nb < 4; ++nb)
          acc[mb][nb] = mfma_bf16(af[mb], bfr[nb], acc[mb][nb]);
    }
  }
  #pragma unroll
  for (int mb = 0; mb < 4; ++mb)
    #pragma unroll
    for (int nb = 0; nb < 4; ++nb)
      #pragma unroll
      for (int r = 0; r < 4; ++r) {
        int row = bm * 128 + wr * 64 + mb * 16 + lg * 4 + r;
        int col = bn * 128 + wc * 64 + nb * 16 + lr;
        size_t idx = (size_t)row * N + col;
        float v = acc[mb][nb][r];
        if constexpr (EPI == 0) ((float*)Cv)[idx] = v;
        else if constexpr (EPI == 1) ((u16*)Cv)[idx] = f2bf(v);
        else ((u16*)Cv)[idx] = f2bf(gelu_tanh(v) * bf2f(aux[idx]));
      }
}

// ---------------- sliding-window GQA flash attention ----------------
// grid (S/64, NH, B), 4 waves x 16 q-rows. K from global (L2), V via v_t [b][kv][HD][S].
__global__ __launch_bounds__(256, 2)
void k_attn(const u16* __restrict__ q_bf, const u16* __restrict__ k_bf,
            const u16* __restrict__ v_t, const int* __restrict__ am,
            u16* __restrict__ attn_o) {
  __shared__ u16 Pl[4][16 * 64];   // per-wave P tile, XOR-swizzled
  int qb = blockIdx.x, h = blockIdx.y, b = blockIdx.z;
  int tid = threadIdx.x, w = tid >> 6, l = tid & 63;
  int lr = l & 15, lg = l >> 4;
  int kvh = h >> 1;
  int q0 = qb * 64 + w * 16;

  bf16x8 qf[8];
  {
    const u16* qp = q_bf + ((size_t)(b * SS + q0 + lr)) * QD + h * 256 + lg * 8;
    #pragma unroll
    for (int ks = 0; ks < 8; ++ks) qf[ks] = *(const bf16x8*)(qp + ks * 32);
  }
  float m[4], ln[4];
  f32x4 oacc[16];
  #pragma unroll
  for (int r = 0; r < 4; ++r) { m[r] = NEGF; ln[r] = 0.f; }
  #pragma unroll
  for (int cb = 0; cb < 16; ++cb) oacc[cb] = (f32x4){0.f, 0.f, 0.f, 0.f};

  int kt_lo = qb >= 16 ? qb - 16 : 0;
  for (int kt = kt_lo; kt <= qb; ++kt) {
    // ---- QK^T ----
    f32x4 sacc[4];
    #pragma unroll
    for (int nb = 0; nb < 4; ++nb) sacc[nb] = (f32x4){0.f, 0.f, 0.f, 0.f};
    const u16* kp0 = k_bf + ((size_t)(b * SS + kt * 64 + lr)) * KD + kvh * 256 + lg * 8;
    #pragma unroll
    for (int ks = 0; ks < 8; ++ks)
      #pragma unroll
      for (int nb = 0; nb < 4; ++nb) {
        bf16x8 kf = *(const bf16x8*)(kp0 + (size_t)nb * 16 * KD + ks * 32);
        sacc[nb] = mfma_bf16(qf[ks], kf, sacc[nb]);
      }
    // ---- mask ----
    float s[4][4];
    #pragma unroll
    for (int nb = 0; nb < 4; ++nb) {
      int key = kt * 64 + nb * 16 + lr;
      int amv = am[b * SS + key];
      #pragma unroll
      for (int r = 0; r < 4; ++r) {
        int sq = q0 + lg * 4 + r;
        int rel = sq - key;
        bool valid = (rel >= 0) && (rel < SW) && (amv > 0);
        s[nb][r] = valid ? sacc[nb][r] : NEGF;
      }
    }
    // ---- online softmax (16-lane row groups) ----
    float scale[4];
    #pragma unroll
    for (int r = 0; r < 4; ++r) {
      float mx = fmaxf(fmaxf(s[0][r], s[1][r]), fmaxf(s[2][r], s[3][r]));
      #pragma unroll
      for (int off = 1; off < 16; off <<= 1) mx = fmaxf(mx, __shfl_xor(mx, off));
      float mnew = fmaxf(m[r], mx);
      scale[r] = __expf(m[r] - mnew);
      float psum = 0.f;
      #pragma unroll
      for (int nb = 0; nb < 4; ++nb) {
        float p = (s[nb][r] > -1e37f) ? __expf(s[nb][r] - mnew) : 0.f;
        s[nb][r] = p; psum += p;
      }
      #pragma unroll
      for (int off = 1; off < 16; off <<= 1) psum += __shfl_xor(psum, off);
      ln[r] = ln[r] * scale[r] + psum;
      m[r] = mnew;
    }
    #pragma unroll
    for (int cb = 0; cb < 16; ++cb)
      #pragma unroll
      for (int r = 0; r < 4; ++r) oacc[cb][r] *= scale[r];
    // ---- P -> LDS (bf16, swizzled) ----
    u16* pw = &Pl[w][0];
    #pragma unroll
    for (int nb = 0; nb < 4; ++nb)
      #pragma unroll
      for (int r = 0; r < 4; ++r) {
        int row = lg * 4 + r, key = nb * 16 + lr;
        pw[(row * 64 + key) ^ ((row & 7) << 3)] = f2bf(s[nb][r]);
      }
    asm volatile("s_waitcnt lgkmcnt(0)" ::: "memory");
    __builtin_amdgcn_sched_barrier(0);
    // ---- PV ----
    #pragma unroll
    for (int ks2 = 0; ks2 < 2; ++ks2) {
      bf16x8 pf = *(const bf16x8*)&pw[(lr * 64 + ks2 * 32 + lg * 8) ^ ((lr & 7) << 3)];
      const u16* vp = v_t + ((size_t)((b * 4 + kvh) * 256 + lr)) * SS + kt * 64 + ks2 * 32 + lg * 8;
      #pragma unroll
      for (int cb = 0; cb < 16; ++cb) {
        bf16x8 vf = *(const bf16x8*)(vp + (size_t)cb * 16 * SS);
        oacc[cb] = mfma_bf16(pf, vf, oacc[cb]);
      }
    }
  }
  // ---- epilogue ----
  #pragma unroll
  for (int cb = 0; cb < 16; ++cb)
    #pragma unroll
    for (int r = 0; r < 4; ++r) {
      int sq = q0 + lg * 4 + r;
      float o = oacc[cb][r] / ln[r];
      attn_o[((size_t)(b * SS + sq)) * QD + h * 256 + cb * 16 + lr] = f2bf(o);
    }
}

// ---------------- launch ----------------
extern "C" void kernel_launch(void* const* d_in, const int* in_sizes, int n_in,
                              void* d_out, int out_size, void* d_ws, size_t ws_size,
                              hipStream_t stream) {
  const float* hs    = (const float*)d_in[0];
  const float* wq    = (const float*)d_in[1];
  const float* wk    = (const float*)d_in[2];
  const float* wv    = (const float*)d_in[3];
  const float* wo    = (const float*)d_in[4];
  const float* wg    = (const float*)d_in[5];
  const float* wu    = (const float*)d_in[6];
  const float* wd    = (const float*)d_in[7];
  const float* ln_in = (const float*)d_in[8];
  const float* ln_pa = (const float*)d_in[9];
  const float* ln_pf = (const float*)d_in[10];
  const float* ln_ff = (const float*)d_in[11];
  const float* qn    = (const float*)d_in[12];
  const float* kn    = (const float*)d_in[13];
  const int*   pid   = (const int*)d_in[14];
  const int*   am    = (const int*)d_in[15];
  float* out = (float*)d_out;
  char* ws = (char*)d_ws;

  // ---- workspace layout: total 199,229,440 B (~190 MiB) ----
  // slab [0, 52.4MB): sequentially reused transposed-weight buffer
  u16* Wslab = (u16*)ws;                                   // up to 2560*10240*2 B
  u16* Xn    = (u16*)(ws + 52428800);                      // [4096][2560] bf16
  char* S0   = ws + 73400320;                              // overlay base
  // phase 1 overlay
  u16*   QKVbf = (u16*)(S0);                               // [4096][4096] bf16
  u16*   Qbf   = (u16*)(S0 + 33554432);                    // [4096][2048]
  u16*   Kbf   = (u16*)(S0 + 50331648);                    // [4096][1024]
  u16*   Vt    = (u16*)(S0 + 58720256);                    // [8][256][2048]
  u16*   AttnO = (u16*)(S0 + 67108864);                    // [4096][2048]
  float* Aproj = (float*)(S0 + 83886080);                  // [4096][2560] f32
  // phase 2 overlay (phase-1 buffers dead by then)
  u16*   UpBf  = (u16*)(S0);                               // [4096][10240] (gate writes in-place)
  float* Mlp   = (float*)(S0 + 83886080);                  // [4096][2560] f32
  float* Hid   = out;                                      // hidden lives in d_out

  dim3 tb(32, 8);
  // ---- phase 1: QKV ----
  k_transpose_w<<<dim3(2048/32, 2560/32), tb, 0, stream>>>(wq, Wslab, 2560, 2048);
  k_transpose_w<<<dim3(1024/32, 2560/32), tb, 0, stream>>>(wk, Wslab + (size_t)2048*2560, 2560, 1024);
  k_transpose_w<<<dim3(1024/32, 2560/32), tb, 0, stream>>>(wv, Wslab + (size_t)3072*2560, 2560, 1024);
  k_rms_in<<<MM, 256, 0, stream>>>(hs, ln_in, Xn);
  k_gemm<1><<<dim3(4096/128, MM/128), 256, 0, stream>>>(Xn, Wslab, QKVbf, nullptr, MM, 4096, 2560);
  k_qknorm_rope<<<MM * 12 / 4, 256, 0, stream>>>(QKVbf, qn, kn, pid, Qbf, Kbf);
  k_transpose_v<<<dim3(SS/32, HD/32, 8), tb, 0, stream>>>(QKVbf, Vt);
  k_attn<<<dim3(SS/64, NH, BB), 256, 0, stream>>>(Qbf, Kbf, Vt, am, AttnO);
  // ---- o-proj (slab now free: Wqkv dead after QKV GEMM) ----
  k_transpose_w<<<dim3(2560/32, 2048/32), tb, 0, stream>>>(wo, Wslab, 2048, 2560);
  k_gemm<0><<<dim3(2560/128, MM/128), 256, 0, stream>>>(AttnO, Wslab, Aproj, nullptr, MM, 2560, 2048);
  k_resid2<<<MM, 256, 0, stream>>>(hs, Aproj, ln_pa, ln_pf, Hid, Xn);
  // ---- phase 2: MLP (slab reused per weight) ----
  k_transpose_w<<<dim3(10240/32, 2560/32), tb, 0, stream>>>(wu, Wslab, 2560, 10240);
  k_gemm<1><<<dim3(10240/128, MM/128), 256, 0, stream>>>(Xn, Wslab, UpBf, nullptr, MM, 10240, 2560);
  k_transpose_w<<<dim3(10240/32, 2560/32), tb, 0, stream>>>(wg, Wslab, 2560, 10240);
  k_gemm<2><<<dim3(10240/128, MM/128), 256, 0, stream>>>(Xn, Wslab, UpBf, UpBf, MM, 10240, 2560);
  k_transpose_w<<<dim3(2560/32, 10240/32), tb, 0, stream>>>(wd, Wslab, 10240, 2560);
  k_gemm<0><<<dim3(2560/128, MM/128), 256, 0, stream>>>(UpBf, Wslab, Mlp, nullptr, MM, 2560, 10240);
  k_final<<<MM, 256, 0, stream>>>(Hid, Mlp, ln_ff);
}